// Round 1
// baseline (428.457 us; speedup 1.0000x reference)
//
#include <hip/hip_runtime.h>

// Problem constants
#define T_LEN   160000          // time samples
#define C_ROWS  256             // channels in x
#define NTHREADS 256            // segments / threads for the IIR scan
#define SEG     (T_LEN / NTHREADS)   // 625 samples per segment
#define PI_D    3.14159265358979323846

// ---------------------------------------------------------------------------
// Kernel 1: compute mod[t] = biquad_lowpass(0.5*noise)[t] + 1.0
// Single workgroup, block-parallel linear recurrence:
//   phase 1: each thread scans its segment with zero y-state  -> affine offset
//   phase 2: thread 0 composes segments via H = A^SEG (f64, exact to f32 coeffs)
//   phase 3: each thread re-scans with true init state, writes mod
// ---------------------------------------------------------------------------
__global__ __launch_bounds__(NTHREADS)
void mod_kernel(const float* __restrict__ noise, float* __restrict__ mod) {
    __shared__ float s_f1[NTHREADS], s_f2[NTHREADS];  // zero-init final states
    __shared__ float s_i1[NTHREADS], s_i2[NTHREADS];  // true init states
    const int t = threadIdx.x;

    // torchaudio lowpass_biquad coefficients, computed in double then cast to
    // float32 (matches numpy reference exactly)
    const double w0    = 2.0 * PI_D * 1.0 / 16000.0;   // cutoff = 0.5*SPEED = 1 Hz
    const double alphaD = sin(w0) / (2.0 * 0.707);
    const double coswD  = cos(w0);
    const double a0D    = 1.0 + alphaD;
    const float b0 = (float)((1.0 - coswD) / 2.0 / a0D);
    const float b1 = (float)((1.0 - coswD) / a0D);
    const float b2 = b0;
    const float a1 = (float)(-2.0 * coswD / a0D);
    const float a2 = (float)((1.0 - alphaD) / a0D);

    const int base = t * SEG;
    // x-history entering this segment (real inputs, not part of the y-scan)
    float px1 = 0.f, px2 = 0.f;
    if (t != 0) {
        px1 = 0.5f * noise[base - 1];
        px2 = 0.5f * noise[base - 2];
    }

    // ---- phase 1: zero y-state scan ----
    {
        float x1 = px1, x2 = px2, y1 = 0.f, y2 = 0.f;
        for (int j = 0; j < SEG; ++j) {
            float xn = 0.5f * noise[base + j];
            float y  = b0 * xn + b1 * x1 + b2 * x2 - a1 * y1 - a2 * y2;
            x2 = x1; x1 = xn; y2 = y1; y1 = y;
        }
        s_f1[t] = y1;   // y at segment end
        s_f2[t] = y2;   // y at segment end - 1
    }
    __syncthreads();

    // ---- phase 2: sequential affine composition over 256 segments ----
    if (t == 0) {
        // H = A^SEG in double, A = [[-a1,-a2],[1,0]] (f32-rounded coefficients)
        double m00 = -(double)a1, m01 = -(double)a2, m10 = 1.0, m11 = 0.0;
        double h00 = 1.0, h01 = 0.0, h10 = 0.0, h11 = 1.0;
        int e = SEG;
        while (e > 0) {
            if (e & 1) {
                double t00 = h00*m00 + h01*m10, t01 = h00*m01 + h01*m11;
                double t10 = h10*m00 + h11*m10, t11 = h10*m01 + h11*m11;
                h00 = t00; h01 = t01; h10 = t10; h11 = t11;
            }
            e >>= 1;
            if (e) {
                double t00 = m00*m00 + m01*m10, t01 = m00*m01 + m01*m11;
                double t10 = m10*m00 + m11*m10, t11 = m10*m01 + m11*m11;
                m00 = t00; m01 = t01; m10 = t10; m11 = t11;
            }
        }
        // scan: state entering segment i  ->  state entering segment i+1
        double s1 = 0.0, s2 = 0.0;   // (y_{-1}, y_{-2}) entering segment 0
        for (int i = 0; i < NTHREADS; ++i) {
            s_i1[i] = (float)s1;
            s_i2[i] = (float)s2;
            double n1 = h00*s1 + h01*s2 + (double)s_f1[i];
            double n2 = h10*s1 + h11*s2 + (double)s_f2[i];
            s1 = n1; s2 = n2;
        }
    }
    __syncthreads();

    // ---- phase 3: true-state scan, write mod = y + OFFSET ----
    {
        float x1 = px1, x2 = px2;
        float y1 = s_i1[t], y2 = s_i2[t];
        for (int j = 0; j < SEG; ++j) {
            float xn = 0.5f * noise[base + j];
            float y  = b0 * xn + b1 * x1 + b2 * x2 - a1 * y1 - a2 * y2;
            mod[base + j] = y + 1.0f;
            x2 = x1; x1 = xn; y2 = y1; y1 = y;
        }
    }
}

// ---------------------------------------------------------------------------
// Kernel 2: out[c,t] = x[c,t] * mod[t]   (memory-bound broadcast multiply)
// One float4 per thread; mod reads hit L1/L2 (640 KB, reused 256x).
// ---------------------------------------------------------------------------
__global__ __launch_bounds__(256)
void mul_kernel(const float4* __restrict__ x4, const float* __restrict__ mod,
                float4* __restrict__ out4) {
    const int f = blockIdx.x * blockDim.x + threadIdx.x;   // float4 index
    const int telem = (f * 4) % T_LEN;                     // column of x, mult of 4
    float4 xv = x4[f];
    float4 mv = *(const float4*)(mod + telem);
    float4 r;
    r.x = xv.x * mv.x;
    r.y = xv.y * mv.y;
    r.z = xv.z * mv.z;
    r.w = xv.w * mv.w;
    out4[f] = r;
}

extern "C" void kernel_launch(void* const* d_in, const int* in_sizes, int n_in,
                              void* d_out, int out_size, void* d_ws, size_t ws_size,
                              hipStream_t stream) {
    const float* x     = (const float*)d_in[0];   // (256, 160000) f32
    const float* noise = (const float*)d_in[1];   // (1, 160000)  f32
    float* out = (float*)d_out;                   // (256, 160000) f32
    float* mod = (float*)d_ws;                    // 160000 f32 scratch (640 KB)

    mod_kernel<<<1, NTHREADS, 0, stream>>>(noise, mod);

    const int total_f4 = (C_ROWS * T_LEN) / 4;    // 10,240,000
    mul_kernel<<<total_f4 / 256, 256, 0, stream>>>(
        (const float4*)x, mod, (float4*)out);
}

// Round 3
// 294.604 us; speedup vs baseline: 1.4543x; 1.4543x over previous
//
#include <hip/hip_runtime.h>
#include <cmath>

// Problem constants
#define T_LEN   160000
#define C_ROWS  256
#define SEG     125                 // samples per segment
#define NSEG    1280                // T_LEN / SEG
#define SCAN_BLOCKS 10
#define SEGS_PER_BLOCK 128          // NSEG / SCAN_BLOCKS
#define CHUNK   5                   // segments per thread in phase 2 (NSEG/256)
#define K2_THREADS 256
#define PI_D    3.14159265358979323846

typedef float fvec4 __attribute__((ext_vector_type(4)));  // nontemporal-capable

struct IIRParams {
    float b0, b1, b2, a1, a2;       // f32-rounded biquad coefficients
    double h00, h01, h10, h11;      // H = A^SEG (f64), A = [[-a1,-a2],[1,0]]
};

// ---------------------------------------------------------------------------
// Phase 1: zero-init scan per segment -> segment offset (f1,f2).
// Coalesced float4 staging of the block's 64 KB noise chunk into LDS first.
// ---------------------------------------------------------------------------
__global__ __launch_bounds__(SEGS_PER_BLOCK)
void iir_phase1(const float* __restrict__ noise,
                float* __restrict__ F1, float* __restrict__ F2,
                IIRParams p) {
    __shared__ float sx[SEGS_PER_BLOCK * SEG];      // 16000 f32 = 62.5 KB
    const int tid = threadIdx.x;
    const int blk = blockIdx.x;
    const int blkBase = blk * SEGS_PER_BLOCK * SEG; // float offset

    const fvec4* n4 = (const fvec4*)(noise + blkBase);
    fvec4* s4 = (fvec4*)sx;
    for (int i = tid; i < (SEGS_PER_BLOCK * SEG) / 4; i += SEGS_PER_BLOCK) {
        fvec4 v = n4[i];
        s4[i] = v * 0.5f;                            // FACTOR (exact)
    }
    __syncthreads();

    const int g = blk * SEGS_PER_BLOCK + tid;       // global segment id
    const int lofs = tid * SEG;
    float px1 = 0.f, px2 = 0.f;                     // x-history entering segment
    if (tid > 0)      { px1 = sx[lofs - 1]; px2 = sx[lofs - 2]; }
    else if (blk > 0) { px1 = 0.5f * noise[blkBase - 1];
                        px2 = 0.5f * noise[blkBase - 2]; }

    float x1 = px1, x2 = px2, y1 = 0.f, y2 = 0.f;
    #pragma unroll 5
    for (int j = 0; j < SEG; ++j) {
        float xn = sx[lofs + j];
        float w  = fmaf(p.b0, xn, fmaf(p.b1, x1, p.b2 * x2));
        float y  = fmaf(-p.a1, y1, fmaf(-p.a2, y2, w));
        x2 = x1; x1 = xn; y2 = y1; y1 = y;
    }
    F1[g] = y1;
    F2[g] = y2;
}

// ---------------------------------------------------------------------------
// Phase 2: compose 1280 affine maps (H, f_g) -> init state per segment.
// Per-thread serial-5 compose, then 256-wide Hillis-Steele scan in f64 LDS.
// ---------------------------------------------------------------------------
__global__ __launch_bounds__(K2_THREADS)
void iir_phase2(const float* __restrict__ F1, const float* __restrict__ F2,
                float* __restrict__ I1, float* __restrict__ I2,
                IIRParams p) {
    __shared__ double sA00[K2_THREADS], sA01[K2_THREADS],
                      sA10[K2_THREADS], sA11[K2_THREADS],
                      sB0[K2_THREADS],  sB1[K2_THREADS];
    const int t = threadIdx.x;
    const double h00 = p.h00, h01 = p.h01, h10 = p.h10, h11 = p.h11;

    double f0[CHUNK], f1v[CHUNK];
    for (int k = 0; k < CHUNK; ++k) {
        f0[k]  = (double)F1[t * CHUNK + k];
        f1v[k] = (double)F2[t * CHUNK + k];
    }
    // chunk map: state -> H^5 * state + b   (segment 5t applied first)
    double A00 = 1, A01 = 0, A10 = 0, A11 = 1, b0v = 0, b1v = 0;
    for (int k = 0; k < CHUNK; ++k) {
        double nb0 = h00 * b0v + h01 * b1v + f0[k];
        double nb1 = h10 * b0v + h11 * b1v + f1v[k];
        b0v = nb0; b1v = nb1;
        double t00 = h00*A00 + h01*A10, t01 = h00*A01 + h01*A11;
        double t10 = h10*A00 + h11*A10, t11 = h10*A01 + h11*A11;
        A00 = t00; A01 = t01; A10 = t10; A11 = t11;
    }
    sA00[t]=A00; sA01[t]=A01; sA10[t]=A10; sA11[t]=A11; sB0[t]=b0v; sB1[t]=b1v;
    __syncthreads();

    // inclusive scan; element t = chunk_0 ∘ ... ∘ chunk_t (chunk_0 first)
    for (int off = 1; off < K2_THREADS; off <<= 1) {
        double pA00=0,pA01=0,pA10=0,pA11=0,pB0=0,pB1=0;
        const bool act = (t >= off);
        if (act) { pA00=sA00[t-off]; pA01=sA01[t-off]; pA10=sA10[t-off];
                   pA11=sA11[t-off]; pB0 =sB0[t-off];  pB1 =sB1[t-off]; }
        double c00=sA00[t], c01=sA01[t], c10=sA10[t], c11=sA11[t],
               cb0=sB0[t],  cb1=sB1[t];
        __syncthreads();
        if (act) {
            // cur ∘ prev : A = c*p, b = c*pb + cb
            sA00[t] = c00*pA00 + c01*pA10;
            sA01[t] = c00*pA01 + c01*pA11;
            sA10[t] = c10*pA00 + c11*pA10;
            sA11[t] = c10*pA01 + c11*pA11;
            sB0[t]  = c00*pB0  + c01*pB1 + cb0;
            sB1[t]  = c10*pB0  + c11*pB1 + cb1;
        }
        __syncthreads();
    }

    // state entering this thread's chunk = exclusive-scan offset (init = 0)
    double s0 = 0.0, s1 = 0.0;
    if (t > 0) { s0 = sB0[t-1]; s1 = sB1[t-1]; }
    for (int k = 0; k < CHUNK; ++k) {
        I1[t * CHUNK + k] = (float)s0;
        I2[t * CHUNK + k] = (float)s1;
        double n0 = h00 * s0 + h01 * s1 + f0[k];
        double n1 = h10 * s0 + h11 * s1 + f1v[k];
        s0 = n0; s1 = n1;
    }
}

// ---------------------------------------------------------------------------
// Phase 3: true-init scan, write mod = y + 1 (in-place in LDS, coalesced out)
// ---------------------------------------------------------------------------
__global__ __launch_bounds__(SEGS_PER_BLOCK)
void iir_phase3(const float* __restrict__ noise,
                const float* __restrict__ I1, const float* __restrict__ I2,
                float* __restrict__ mod, IIRParams p) {
    __shared__ float sx[SEGS_PER_BLOCK * SEG];
    const int tid = threadIdx.x;
    const int blk = blockIdx.x;
    const int blkBase = blk * SEGS_PER_BLOCK * SEG;

    const fvec4* n4 = (const fvec4*)(noise + blkBase);
    fvec4* s4 = (fvec4*)sx;
    for (int i = tid; i < (SEGS_PER_BLOCK * SEG) / 4; i += SEGS_PER_BLOCK) {
        fvec4 v = n4[i];
        s4[i] = v * 0.5f;
    }
    __syncthreads();

    const int g = blk * SEGS_PER_BLOCK + tid;
    const int lofs = tid * SEG;
    float px1 = 0.f, px2 = 0.f;
    if (tid > 0)      { px1 = sx[lofs - 1]; px2 = sx[lofs - 2]; }
    else if (blk > 0) { px1 = 0.5f * noise[blkBase - 1];
                        px2 = 0.5f * noise[blkBase - 2]; }
    __syncthreads();   // all history reads done before in-place overwrite

    float x1 = px1, x2 = px2, y1 = I1[g], y2 = I2[g];
    for (int j = 0; j < SEG; ++j) {
        float xn = sx[lofs + j];
        float w  = fmaf(p.b0, xn, fmaf(p.b1, x1, p.b2 * x2));
        float y  = fmaf(-p.a1, y1, fmaf(-p.a2, y2, w));
        sx[lofs + j] = y + 1.0f;                    // mod value, in place
        x2 = x1; x1 = xn; y2 = y1; y1 = y;
    }
    __syncthreads();

    fvec4* m4 = (fvec4*)(mod + blkBase);
    for (int i = tid; i < (SEGS_PER_BLOCK * SEG) / 4; i += SEGS_PER_BLOCK) {
        m4[i] = s4[i];
    }
}

// ---------------------------------------------------------------------------
// out[c,t] = x[c,t] * mod[t]  — memory-bound; nt hints keep mod cached
// ---------------------------------------------------------------------------
__global__ __launch_bounds__(256)
void mul_kernel(const fvec4* __restrict__ x4, const float* __restrict__ mod,
                fvec4* __restrict__ out4) {
    const int f = blockIdx.x * blockDim.x + threadIdx.x;   // float4 index
    const int telem = (f * 4) % T_LEN;
    fvec4 xv = __builtin_nontemporal_load(&x4[f]);
    fvec4 mv = *(const fvec4*)(mod + telem);
    fvec4 r = xv * mv;
    __builtin_nontemporal_store(r, &out4[f]);
}

extern "C" void kernel_launch(void* const* d_in, const int* in_sizes, int n_in,
                              void* d_out, int out_size, void* d_ws, size_t ws_size,
                              hipStream_t stream) {
    const float* x     = (const float*)d_in[0];   // (256, 160000) f32
    const float* noise = (const float*)d_in[1];   // (1, 160000)  f32
    float* out = (float*)d_out;
    float* mod = (float*)d_ws;                    // 160000 f32
    float* F1  = mod + T_LEN;                     // NSEG f32 each
    float* F2  = F1 + NSEG;
    float* I1  = F2 + NSEG;
    float* I2  = I1 + NSEG;

    // Host-side coefficient + H = A^SEG computation (baked into graph args)
    IIRParams p;
    {
        const double w0    = 2.0 * PI_D * 1.0 / 16000.0;  // cutoff = 1 Hz
        const double alpha = sin(w0) / (2.0 * 0.707);
        const double cosw  = cos(w0);
        const double a0    = 1.0 + alpha;
        p.b0 = (float)((1.0 - cosw) / 2.0 / a0);
        p.b1 = (float)((1.0 - cosw) / a0);
        p.b2 = p.b0;
        p.a1 = (float)(-2.0 * cosw / a0);
        p.a2 = (float)((1.0 - alpha) / a0);

        double m00 = -(double)p.a1, m01 = -(double)p.a2, m10 = 1.0, m11 = 0.0;
        double h00 = 1, h01 = 0, h10 = 0, h11 = 1;
        int e = SEG;
        while (e > 0) {
            if (e & 1) {
                double t00 = h00*m00 + h01*m10, t01 = h00*m01 + h01*m11;
                double t10 = h10*m00 + h11*m10, t11 = h10*m01 + h11*m11;
                h00 = t00; h01 = t01; h10 = t10; h11 = t11;
            }
            e >>= 1;
            if (e) {
                double t00 = m00*m00 + m01*m10, t01 = m00*m01 + m01*m11;
                double t10 = m10*m00 + m11*m10, t11 = m10*m01 + m11*m11;
                m00 = t00; m01 = t01; m10 = t10; m11 = t11;
            }
        }
        p.h00 = h00; p.h01 = h01; p.h10 = h10; p.h11 = h11;
    }

    iir_phase1<<<SCAN_BLOCKS, SEGS_PER_BLOCK, 0, stream>>>(noise, F1, F2, p);
    iir_phase2<<<1, K2_THREADS, 0, stream>>>(F1, F2, I1, I2, p);
    iir_phase3<<<SCAN_BLOCKS, SEGS_PER_BLOCK, 0, stream>>>(noise, I1, I2, mod, p);

    const int total_f4 = (C_ROWS * T_LEN) / 4;    // 10,240,000
    mul_kernel<<<total_f4 / 256, 256, 0, stream>>>(
        (const fvec4*)x, mod, (fvec4*)out);
}